// Round 11
// baseline (386.808 us; speedup 1.0000x reference)
//
#include <hip/hip_runtime.h>
#include <hip/hip_fp16.h>

#define IMH 480
#define IMW 640
#define HW (IMH*IMW)
#define NB 16

// iter_kernel geometry (round-7 proven): 100 blocks/batch * 256 thr * 4 px * 3 groups == HW
#define BPB 100
#define TPX 4
#define GROUPS 3
#define THREADS_PB (BPB*256)          // 25600 threads per batch
#define GSTRIDE (THREADS_PB*TPX)      // 102400 px per group = 160 rows
#define GROWS (GSTRIDE/IMW)           // 160

// ---- order-preserving float<->uint encoding (for atomic min/max) ----
__device__ inline unsigned fenc(float x){
    unsigned u = __float_as_uint(x);
    return (u & 0x80000000u) ? ~u : (u | 0x80000000u);
}
__device__ inline float fdec(unsigned e){
    unsigned u = (e & 0x80000000u) ? (e & 0x7FFFFFFFu) : ~e;
    return __uint_as_float(u);
}

// ---- init: copy R,t to state, zero accumulators, init min/max ----
__global__ void init_kernel(const float* __restrict__ Rin, const float* __restrict__ tin,
                            float* __restrict__ stateR, float* __restrict__ statet,
                            unsigned* __restrict__ mm, float* __restrict__ acc){
    int i = threadIdx.x;
    if (i < NB*9) stateR[i] = Rin[i];
    if (i < NB*3) statet[i] = tin[i];
    if (i == 0){ mm[0] = 0xFFFFFFFFu; mm[1] = 0u; }
    for (int k = i; k < NB*27; k += 256) acc[k] = 0.f;
}

// ---- global min/max of depth1: float4 loads, block combine, 1 atomic/block.
// 256 blocks: atomic tail = 256 serialized same-address ops ~ 6.4 us (1024 blocks cost ~26 us - R10 regression)
__global__ __launch_bounds__(256) void minmax_kernel(const float4* __restrict__ d, unsigned* __restrict__ mm){
    unsigned lmin = 0xFFFFFFFFu, lmax = 0u;
    const int total4 = NB*HW/4;
    for (int i = blockIdx.x*256 + threadIdx.x; i < total4; i += gridDim.x*256){
        float4 v = d[i];
        unsigned e0 = fenc(v.x), e1 = fenc(v.y), e2 = fenc(v.z), e3 = fenc(v.w);
        lmin = min(lmin, min(min(e0,e1), min(e2,e3)));
        lmax = max(lmax, max(max(e0,e1), max(e2,e3)));
    }
    #pragma unroll
    for (int off = 32; off; off >>= 1){
        lmin = min(lmin, (unsigned)__shfl_down((int)lmin, off));
        lmax = max(lmax, (unsigned)__shfl_down((int)lmax, off));
    }
    __shared__ unsigned smin[4], smax[4];
    int wave = threadIdx.x >> 6, lane = threadIdx.x & 63;
    if (lane == 0){ smin[wave] = lmin; smax[wave] = lmax; }
    __syncthreads();
    if (threadIdx.x == 0){
        unsigned bmin = min(min(smin[0],smin[1]), min(smin[2],smin[3]));
        unsigned bmax = max(max(smax[0],smax[1]), max(smax[2],smax[3]));
        atomicMin(&mm[0], bmin);
        atomicMax(&mm[1], bmax);
    }
}

// ---- fused texel uint2 {f32 depth1, 3x snorm8 normal}: one 8-B aligned gather per corner ----
__global__ __launch_bounds__(256) void normal_kernel(const float* __restrict__ depth1,
                                                     const float* __restrict__ Kp,
                                                     const unsigned* __restrict__ mm,
                                                     uint2* __restrict__ tex,
                                                     float* __restrict__ weights){
    int b = blockIdx.y;
    int pix = blockIdx.x*256 + threadIdx.x;
    int r = pix / IMW, c = pix % IMW;
    const float fx = Kp[b*4+0], fy = Kp[b*4+1], cx = Kp[b*4+2], cy = Kp[b*4+3];
    const float inv_fx = 1.f/fx, inv_fy = 1.f/fy;
    const float* __restrict__ d = depth1 + (size_t)b*HW;
    int rm = max(r-1,0), rp = min(r+1,IMH-1), cm = max(c-1,0), cp = min(c+1,IMW-1);

    auto vert = [&](int rr, int cc, float v[3]){
        float dd = d[rr*IMW+cc];
        v[0] = ((float)cc - cx)*inv_fx*dd;
        v[1] = ((float)rr - cy)*inv_fy*dd;
        v[2] = dd;
    };
    float va[3],vb[3],vc2[3],vd[3],ve[3],vf[3],vg[3],vh[3];
    vert(rm,cm,va); vert(rm,c,vb);  vert(rm,cp,vc2);
    vert(r ,cm,vd);                 vert(r ,cp,ve);
    vert(rp,cm,vf); vert(rp,c,vg);  vert(rp,cp,vh);

    float dx[3], dy[3];
    #pragma unroll
    for (int k=0;k<3;k++){
        dx[k] = (vc2[k]-va[k]) + 2.f*(ve[k]-vd[k]) + (vh[k]-vf[k]);
        dy[k] = (vf[k]-va[k]) + 2.f*(vg[k]-vb[k]) + (vh[k]-vc2[k]);
    }
    float nx = dx[1]*dy[2] - dx[2]*dy[1];
    float ny = dx[2]*dy[0] - dx[0]*dy[2];
    float nz = dx[0]*dy[1] - dx[1]*dy[0];
    float mag = sqrtf(nx*nx + ny*ny + nz*nz + 1e-16f);
    float inv = __builtin_amdgcn_rcpf(mag + 1e-8f);
    nx *= inv; ny *= inv; nz *= inv;

    float dc = d[r*IMW+c];
    float dmin = fdec(mm[0]), dmax = fdec(mm[1]);
    if (dc == dmin || dc == dmax){ nx = 0.f; ny = 0.f; nz = 0.f; }

    // pack as 3x snorm8 (scale 127)
    int qx = (int)rintf(nx*127.f);
    int qy = (int)rintf(ny*127.f);
    int qz = (int)rintf(nz*127.f);
    uint2 p;
    p.x = __float_as_uint(dc);
    p.y = ((unsigned)(qx & 0xFF)) | ((unsigned)(qy & 0xFF) << 8) | ((unsigned)(qz & 0xFF) << 16);
    tex[(size_t)b*HW + pix] = p;
    weights[(size_t)b*HW + pix] = 1.f;
}

// ---- per-pixel ICP residual/Jacobian; 4-px groups for ILP; one 8-B gather per corner ----
__global__ __launch_bounds__(256) void iter_kernel(const float4* __restrict__ depth0_v4,
                                                   const uint2* __restrict__ tex,
                                                   const float* __restrict__ Kp,
                                                   const float* __restrict__ stateR,
                                                   const float* __restrict__ statet,
                                                   float* __restrict__ acc){
    const int b = blockIdx.y;
    const float fx = Kp[b*4+0], fy = Kp[b*4+1], cx = Kp[b*4+2], cy = Kp[b*4+3];
    const float inv_fx = 1.f/fx, inv_fy = 1.f/fy;
    float Rm[9];
    #pragma unroll
    for (int i=0;i<9;i++) Rm[i] = stateR[b*9+i];
    float tv[3];
    #pragma unroll
    for (int i=0;i<3;i++) tv[i] = statet[b*3+i];

    const float4* __restrict__ d0v = depth0_v4 + (size_t)b*(HW/4);
    const uint2* __restrict__ tb   = tex + (size_t)b*HW;

    float accv[27];
    #pragma unroll
    for (int i=0;i<27;i++) accv[i] = 0.f;

    const int tid = blockIdx.x*256 + threadIdx.x;     // 0..25599
    const int base0 = tid*TPX;
    const int c0 = base0 % IMW;                        // same row for all 4 px (640%4==0)
    const int r0 = base0 / IMW;
    const float px_base = ((float)c0 - cx)*inv_fx;
    float pyv = ((float)r0 - cy)*inv_fy;
    const float py_step = (float)GROWS*inv_fy;
    const float inv127 = 1.f/127.f;

    #pragma unroll 1
    for (int g = 0; g < GROUPS; g++){
        float4 d4 = d0v[tid + g*THREADS_PB];
        float dd[4] = {d4.x, d4.y, d4.z, d4.w};

        #pragma unroll
        for (int j = 0; j < TPX; j++){
            float d0 = dd[j];
            float V0x = (px_base + (float)j*inv_fx)*d0;
            float V0y = pyv*d0;
            float V0z = d0;

            float X = Rm[0]*V0x + Rm[1]*V0y + Rm[2]*V0z + tv[0];
            float Y = Rm[3]*V0x + Rm[4]*V0y + Rm[5]*V0z + tv[1];
            float Z = Rm[6]*V0x + Rm[7]*V0y + Rm[8]*V0z + tv[2];
            float invZ = __builtin_amdgcn_rcpf(Z);
            float uu = X*invZ*fx + cx;
            float vv = Y*invZ*fy + cy;

            bool inview = (uu > 0.f) && (uu < (float)(IMW-1)) && (vv > 0.f) && (vv < (float)(IMH-1));

            float J0=0.f,J1=0.f,J2=0.f,J3=0.f,J4=0.f,J5=0.f,wres=0.f;
            if (inview){
                float u0f = floorf(uu), v0f = floorf(vv);
                int u0 = (int)u0f, v0 = (int)v0f;
                float wu = uu - u0f, wv = vv - v0f;
                float w00 = (1.f-wu)*(1.f-wv), w10 = wu*(1.f-wv), w01 = (1.f-wu)*wv, w11 = wu*wv;
                int i00 = v0*IMW + u0;

                uint2 t00 = tb[i00], t10 = tb[i00+1], t01 = tb[i00+IMW], t11 = tb[i00+IMW+1];

                float d00 = __uint_as_float(t00.x), d10 = __uint_as_float(t10.x);
                float d01 = __uint_as_float(t01.x), d11 = __uint_as_float(t11.x);

                float pxa = (u0f - cx)*inv_fx, pxb = pxa + inv_fx;
                float pya = (v0f - cy)*inv_fy, pyb = pya + inv_fy;
                float a = w00*d00, bb = w10*d10, cc = w01*d01, ee = w11*d11;
                float rVz = (a + bb) + (cc + ee);
                float rVx = (a + cc)*pxa + (bb + ee)*pxb;
                float rVy = (a + bb)*pya + (cc + ee)*pyb;

                // decode snorm8 normals (scale deferred to after bilinear blend)
                float q00x = (float)((int)(t00.y << 24) >> 24);
                float q00y = (float)((int)(t00.y << 16) >> 24);
                float q00z = (float)((int)(t00.y <<  8) >> 24);
                float q10x = (float)((int)(t10.y << 24) >> 24);
                float q10y = (float)((int)(t10.y << 16) >> 24);
                float q10z = (float)((int)(t10.y <<  8) >> 24);
                float q01x = (float)((int)(t01.y << 24) >> 24);
                float q01y = (float)((int)(t01.y << 16) >> 24);
                float q01z = (float)((int)(t01.y <<  8) >> 24);
                float q11x = (float)((int)(t11.y << 24) >> 24);
                float q11y = (float)((int)(t11.y << 16) >> 24);
                float q11z = (float)((int)(t11.y <<  8) >> 24);

                float n0x = (w00*q00x + w10*q10x + w01*q01x + w11*q11x) * inv127;
                float n0y = (w00*q00y + w10*q10y + w01*q01y + w11*q11y) * inv127;
                float n0z = (w00*q00z + w10*q10z + w01*q01z + w11*q11z) * inv127;

                float dfx = X - rVx, dfy = Y - rVy, dfz = Z - rVz;
                float d2 = dfx*dfx + dfy*dfy + dfz*dfz + 1e-16f;
                if (d2 <= 0.01f){
                    float res = n0x*dfx + n0y*dfy + n0z*dfz;
                    float N0 = n0x*Rm[0] + n0y*Rm[3] + n0z*Rm[6];
                    float N1 = n0x*Rm[1] + n0y*Rm[4] + n0z*Rm[7];
                    float N2 = n0x*Rm[2] + n0y*Rm[5] + n0z*Rm[8];
                    float cr0 = N1*V0z - N2*V0y;
                    float cr1 = N2*V0x - N0*V0z;
                    float cr2 = N0*V0y - N1*V0x;
                    float ndot = fabsf(N2);
                    float dsh = d0 - 0.4f;
                    float sigz = 0.0012f + 0.0019f*dsh*dsh;
                    float sigma = ndot*sigz + 0.001f;
                    float invs = __builtin_amdgcn_rcpf(sigma + 1e-8f);
                    wres = res*invs;
                    J0 = -cr0*invs; J1 = -cr1*invs; J2 = -cr2*invs;
                    J3 =  N0*invs;  J4 =  N1*invs;  J5 =  N2*invs;
                }
            }

            float Jv[6] = {J0,J1,J2,J3,J4,J5};
            int idx = 0;
            #pragma unroll
            for (int k=0;k<6;k++)
                #pragma unroll
                for (int l=k;l<6;l++){ accv[idx] += Jv[k]*Jv[l]; idx++; }
            #pragma unroll
            for (int k=0;k<6;k++){ accv[idx] += Jv[k]*wres; idx++; }
        }

        pyv += py_step;
    }

    // one wave-level reduction per thread (amortized over 12 pixels)
    #pragma unroll
    for (int i=0;i<27;i++){
        float v = accv[i];
        #pragma unroll
        for (int off=32; off; off >>= 1) v += __shfl_down(v, off);
        accv[i] = v;
    }

    __shared__ float sacc[4][27];
    int wave = threadIdx.x >> 6, lane = threadIdx.x & 63;
    if (lane == 0){
        #pragma unroll
        for (int i=0;i<27;i++) sacc[wave][i] = accv[i];
    }
    __syncthreads();
    if (threadIdx.x < 27){
        float s = sacc[0][threadIdx.x] + sacc[1][threadIdx.x]
                + sacc[2][threadIdx.x] + sacc[3][threadIdx.x];
        atomicAdd(&acc[b*27 + threadIdx.x], s);
    }
}

// ---- per-batch 6x6 solve (f32 Cholesky, fully unrolled -> registers only) + twist update ----
__global__ void solve_kernel(float* __restrict__ acc,
                             float* __restrict__ stateR, float* __restrict__ statet,
                             float* __restrict__ outR, float* __restrict__ outt){
    int b = threadIdx.x;
    if (b >= NB) return;

    float a27[27];
    #pragma unroll
    for (int i=0;i<27;i++) a27[i] = acc[b*27+i];
    #pragma unroll
    for (int i=0;i<27;i++) acc[b*27+i] = 0.f;   // zero for next iteration

    float A[6][6], rhs[6];
    int idx = 0;
    #pragma unroll
    for (int k=0;k<6;k++)
        #pragma unroll
        for (int l=k;l<6;l++){ A[k][l] = a27[idx]; A[l][k] = a27[idx]; idx++; }
    #pragma unroll
    for (int k=0;k<6;k++) rhs[k] = a27[21+k];

    float tr = 0.f;
    #pragma unroll
    for (int k=0;k<6;k++) tr += A[k][k];
    float lm = tr*1e-6f;
    #pragma unroll
    for (int k=0;k<6;k++) A[k][k] += lm;

    // Cholesky A = L L^T (SPD after damping)
    float L[6][6];
    #pragma unroll
    for (int i=0;i<6;i++){
        #pragma unroll
        for (int j=0;j<=i;j++){
            float s = A[i][j];
            #pragma unroll
            for (int k=0;k<j;k++) s -= L[i][k]*L[j][k];
            if (i == j) L[i][i] = sqrtf(s);
            else        L[i][j] = s / L[j][j];
        }
    }
    float y[6];
    #pragma unroll
    for (int i=0;i<6;i++){
        float s = rhs[i];
        #pragma unroll
        for (int k=0;k<i;k++) s -= L[i][k]*y[k];
        y[i] = s / L[i][i];
    }
    float xi[6];
    #pragma unroll
    for (int ii=5; ii>=0; ii--){
        float s = y[ii];
        #pragma unroll
        for (int k=ii+1;k<6;k++) s -= L[k][ii]*xi[k];
        xi[ii] = s / L[ii][ii];
    }

    float w0 = -xi[0], w1 = -xi[1], w2 = -xi[2];
    float th = sqrtf(w0*w0 + w1*w1 + w2*w2 + 1e-24f);
    float ith = 1.f/th;
    float kx = w0*ith, ky = w1*ith, kz = w2*ith;
    float s = sinf(th), cm1 = 1.f - cosf(th);
    float dRm[9];
    dRm[0] = 1.f + cm1*(-ky*ky - kz*kz);
    dRm[1] = -s*kz + cm1*(kx*ky);
    dRm[2] =  s*ky + cm1*(kx*kz);
    dRm[3] =  s*kz + cm1*(kx*ky);
    dRm[4] = 1.f + cm1*(-kx*kx - kz*kz);
    dRm[5] = -s*kx + cm1*(ky*kz);
    dRm[6] = -s*ky + cm1*(kx*kz);
    dRm[7] =  s*kx + cm1*(ky*kz);
    dRm[8] = 1.f + cm1*(-kx*kx - ky*ky);

    float dt0 = -(dRm[0]*xi[3] + dRm[1]*xi[4] + dRm[2]*xi[5]);
    float dt1 = -(dRm[3]*xi[3] + dRm[4]*xi[4] + dRm[5]*xi[5]);
    float dt2 = -(dRm[6]*xi[3] + dRm[7]*xi[4] + dRm[8]*xi[5]);

    float Rm[9], tv[3];
    #pragma unroll
    for (int i=0;i<9;i++) Rm[i] = stateR[b*9+i];
    #pragma unroll
    for (int i=0;i<3;i++) tv[i] = statet[b*3+i];

    float Rn[9];
    #pragma unroll
    for (int i=0;i<3;i++)
        #pragma unroll
        for (int j=0;j<3;j++)
            Rn[i*3+j] = Rm[i*3+0]*dRm[0*3+j] + Rm[i*3+1]*dRm[1*3+j] + Rm[i*3+2]*dRm[2*3+j];
    float tn0 = Rm[0]*dt0 + Rm[1]*dt1 + Rm[2]*dt2 + tv[0];
    float tn1 = Rm[3]*dt0 + Rm[4]*dt1 + Rm[5]*dt2 + tv[1];
    float tn2 = Rm[6]*dt0 + Rm[7]*dt1 + Rm[8]*dt2 + tv[2];

    #pragma unroll
    for (int i=0;i<9;i++){ stateR[b*9+i] = Rn[i]; outR[b*9+i] = Rn[i]; }
    statet[b*3+0] = tn0; outt[b*3+0] = tn0;
    statet[b*3+1] = tn1; outt[b*3+1] = tn1;
    statet[b*3+2] = tn2; outt[b*3+2] = tn2;
}

extern "C" void kernel_launch(void* const* d_in, const int* in_sizes, int n_in,
                              void* d_out, int out_size, void* d_ws, size_t ws_size,
                              hipStream_t stream){
    const float* depth0 = (const float*)d_in[0];
    const float* depth1 = (const float*)d_in[1];
    const float* Kp     = (const float*)d_in[2];
    const float* Rin    = (const float*)d_in[3];
    const float* tin    = (const float*)d_in[4];

    float* out     = (float*)d_out;
    float* outR    = out;
    float* outt    = out + NB*9;
    float* weights = out + NB*12;

    uint2* tex     = (uint2*)d_ws;                        // NB*HW uint2 (8 B/px, ~39 MB)
    float* stateR  = (float*)(tex + (size_t)NB*HW);       // NB*9
    float* statet  = stateR + NB*9;                       // NB*3
    unsigned* mm   = (unsigned*)(statet + NB*3);          // 2
    float* acc     = (float*)(mm + 2);                    // NB*27

    init_kernel<<<1, 256, 0, stream>>>(Rin, tin, stateR, statet, mm, acc);
    minmax_kernel<<<dim3(256), 256, 0, stream>>>((const float4*)depth1, mm);
    normal_kernel<<<dim3(HW/256, NB), 256, 0, stream>>>(depth1, Kp, mm, tex, weights);
    for (int it = 0; it < 3; it++){
        iter_kernel<<<dim3(BPB, NB), 256, 0, stream>>>((const float4*)depth0, tex, Kp, stateR, statet, acc);
        solve_kernel<<<1, 64, 0, stream>>>(acc, stateR, statet, outR, outt);
    }
}

// Round 12
// 241.391 us; speedup vs baseline: 1.6024x; 1.6024x over previous
//
#include <hip/hip_runtime.h>
#include <hip/hip_fp16.h>

#define IMH 480
#define IMW 640
#define HW (IMH*IMW)
#define NB 16

// iter_kernel geometry (round-7 proven): 100 blocks/batch * 256 thr * 4 px * 3 groups == HW
#define BPB 100
#define TPX 4
#define GROUPS 3
#define THREADS_PB (BPB*256)          // 25600 threads per batch
#define GSTRIDE (THREADS_PB*TPX)      // 102400 px per group = 160 rows
#define GROWS (GSTRIDE/IMW)           // 160

// ---- order-preserving float<->uint encoding (for atomic min/max) ----
__device__ inline unsigned fenc(float x){
    unsigned u = __float_as_uint(x);
    return (u & 0x80000000u) ? ~u : (u | 0x80000000u);
}
__device__ inline float fdec(unsigned e){
    unsigned u = (e & 0x80000000u) ? (e & 0x7FFFFFFFu) : ~e;
    return __uint_as_float(u);
}

// ---- init: copy R,t to state, zero accumulators, init min/max ----
__global__ void init_kernel(const float* __restrict__ Rin, const float* __restrict__ tin,
                            float* __restrict__ stateR, float* __restrict__ statet,
                            unsigned* __restrict__ mm, float* __restrict__ acc){
    int i = threadIdx.x;
    if (i < NB*9) stateR[i] = Rin[i];
    if (i < NB*3) statet[i] = tin[i];
    if (i == 0){ mm[0] = 0xFFFFFFFFu; mm[1] = 0u; }
    for (int k = i; k < NB*27; k += 256) acc[k] = 0.f;
}

// ---- global min/max of depth1: float4 loads, block combine, 1 atomic/block.
// 256 blocks: atomic tail ~6.4 us (1024 blocks cost ~26 us - R10/R11 lesson: same-address atomics ~25 ns each)
__global__ __launch_bounds__(256) void minmax_kernel(const float4* __restrict__ d, unsigned* __restrict__ mm){
    unsigned lmin = 0xFFFFFFFFu, lmax = 0u;
    const int total4 = NB*HW/4;
    for (int i = blockIdx.x*256 + threadIdx.x; i < total4; i += gridDim.x*256){
        float4 v = d[i];
        unsigned e0 = fenc(v.x), e1 = fenc(v.y), e2 = fenc(v.z), e3 = fenc(v.w);
        lmin = min(lmin, min(min(e0,e1), min(e2,e3)));
        lmax = max(lmax, max(max(e0,e1), max(e2,e3)));
    }
    #pragma unroll
    for (int off = 32; off; off >>= 1){
        lmin = min(lmin, (unsigned)__shfl_down((int)lmin, off));
        lmax = max(lmax, (unsigned)__shfl_down((int)lmax, off));
    }
    __shared__ unsigned smin[4], smax[4];
    int wave = threadIdx.x >> 6, lane = threadIdx.x & 63;
    if (lane == 0){ smin[wave] = lmin; smax[wave] = lmax; }
    __syncthreads();
    if (threadIdx.x == 0){
        unsigned bmin = min(min(smin[0],smin[1]), min(smin[2],smin[3]));
        unsigned bmax = max(max(smax[0],smax[1]), max(smax[2],smax[3]));
        atomicMin(&mm[0], bmin);
        atomicMax(&mm[1], bmax);
    }
}

// ---- normal1 packed 3x biased-ubyte (q+127) in one uint (4 B/px): decode = v_cvt_f32_ubyte# ----
__global__ __launch_bounds__(256) void normal_kernel(const float* __restrict__ depth1,
                                                     const float* __restrict__ Kp,
                                                     const unsigned* __restrict__ mm,
                                                     unsigned* __restrict__ nrm,
                                                     float* __restrict__ weights){
    int b = blockIdx.y;
    int pix = blockIdx.x*256 + threadIdx.x;
    int r = pix / IMW, c = pix % IMW;
    const float fx = Kp[b*4+0], fy = Kp[b*4+1], cx = Kp[b*4+2], cy = Kp[b*4+3];
    const float inv_fx = 1.f/fx, inv_fy = 1.f/fy;
    const float* __restrict__ d = depth1 + (size_t)b*HW;
    int rm = max(r-1,0), rp = min(r+1,IMH-1), cm = max(c-1,0), cp = min(c+1,IMW-1);

    auto vert = [&](int rr, int cc, float v[3]){
        float dd = d[rr*IMW+cc];
        v[0] = ((float)cc - cx)*inv_fx*dd;
        v[1] = ((float)rr - cy)*inv_fy*dd;
        v[2] = dd;
    };
    float va[3],vb[3],vc2[3],vd[3],ve[3],vf[3],vg[3],vh[3];
    vert(rm,cm,va); vert(rm,c,vb);  vert(rm,cp,vc2);
    vert(r ,cm,vd);                 vert(r ,cp,ve);
    vert(rp,cm,vf); vert(rp,c,vg);  vert(rp,cp,vh);

    float dx[3], dy[3];
    #pragma unroll
    for (int k=0;k<3;k++){
        dx[k] = (vc2[k]-va[k]) + 2.f*(ve[k]-vd[k]) + (vh[k]-vf[k]);
        dy[k] = (vf[k]-va[k]) + 2.f*(vg[k]-vb[k]) + (vh[k]-vc2[k]);
    }
    float nx = dx[1]*dy[2] - dx[2]*dy[1];
    float ny = dx[2]*dy[0] - dx[0]*dy[2];
    float nz = dx[0]*dy[1] - dx[1]*dy[0];
    float mag = sqrtf(nx*nx + ny*ny + nz*nz + 1e-16f);
    float inv = __builtin_amdgcn_rcpf(mag + 1e-8f);
    nx *= inv; ny *= inv; nz *= inv;

    float dc = d[r*IMW+c];
    float dmin = fdec(mm[0]), dmax = fdec(mm[1]);
    if (dc == dmin || dc == dmax){ nx = 0.f; ny = 0.f; nz = 0.f; }

    // pack as 3x biased ubyte: q = round(n*127)+127 in [0,254]
    int qx = (int)rintf(nx*127.f) + 127;
    int qy = (int)rintf(ny*127.f) + 127;
    int qz = (int)rintf(nz*127.f) + 127;
    unsigned p = ((unsigned)qx) | ((unsigned)qy << 8) | ((unsigned)qz << 16);
    nrm[(size_t)b*HW + pix] = p;
    weights[(size_t)b*HW + pix] = 1.f;
}

// ---- per-pixel ICP residual/Jacobian; 4-px groups for ILP; 4-B texel gathers (fast path) ----
__global__ __launch_bounds__(256) void iter_kernel(const float4* __restrict__ depth0_v4,
                                                   const float* __restrict__ depth1,
                                                   const unsigned* __restrict__ nrm,
                                                   const float* __restrict__ Kp,
                                                   const float* __restrict__ stateR,
                                                   const float* __restrict__ statet,
                                                   float* __restrict__ acc){
    const int b = blockIdx.y;
    const float fx = Kp[b*4+0], fy = Kp[b*4+1], cx = Kp[b*4+2], cy = Kp[b*4+3];
    const float inv_fx = 1.f/fx, inv_fy = 1.f/fy;
    float Rm[9];
    #pragma unroll
    for (int i=0;i<9;i++) Rm[i] = stateR[b*9+i];
    float tv[3];
    #pragma unroll
    for (int i=0;i<3;i++) tv[i] = statet[b*3+i];

    const float4* __restrict__ d0v = depth0_v4 + (size_t)b*(HW/4);
    const float* __restrict__ d1   = depth1 + (size_t)b*HW;
    const unsigned* __restrict__ nb_ = nrm + (size_t)b*HW;

    float accv[27];
    #pragma unroll
    for (int i=0;i<27;i++) accv[i] = 0.f;

    const int tid = blockIdx.x*256 + threadIdx.x;     // 0..25599
    const int base0 = tid*TPX;
    const int c0 = base0 % IMW;                        // same row for all 4 px (640%4==0)
    const int r0 = base0 / IMW;
    const float px_base = ((float)c0 - cx)*inv_fx;
    float pyv = ((float)r0 - cy)*inv_fy;
    const float py_step = (float)GROWS*inv_fy;
    const float inv127 = 1.f/127.f;

    #pragma unroll 1
    for (int g = 0; g < GROUPS; g++){
        float4 d4 = d0v[tid + g*THREADS_PB];
        float dd[4] = {d4.x, d4.y, d4.z, d4.w};

        #pragma unroll
        for (int j = 0; j < TPX; j++){
            float d0 = dd[j];
            float V0x = (px_base + (float)j*inv_fx)*d0;
            float V0y = pyv*d0;
            float V0z = d0;

            float X = Rm[0]*V0x + Rm[1]*V0y + Rm[2]*V0z + tv[0];
            float Y = Rm[3]*V0x + Rm[4]*V0y + Rm[5]*V0z + tv[1];
            float Z = Rm[6]*V0x + Rm[7]*V0y + Rm[8]*V0z + tv[2];
            float invZ = __builtin_amdgcn_rcpf(Z);
            float uu = X*invZ*fx + cx;
            float vv = Y*invZ*fy + cy;

            bool inview = (uu > 0.f) && (uu < (float)(IMW-1)) && (vv > 0.f) && (vv < (float)(IMH-1));

            float J0=0.f,J1=0.f,J2=0.f,J3=0.f,J4=0.f,J5=0.f,wres=0.f;
            if (inview){
                float u0f = floorf(uu), v0f = floorf(vv);
                int u0 = (int)u0f, v0 = (int)v0f;
                float wu = uu - u0f, wv = vv - v0f;
                float w00 = (1.f-wu)*(1.f-wv), w10 = wu*(1.f-wv), w01 = (1.f-wu)*wv, w11 = wu*wv;
                int i00 = v0*IMW + u0;

                float d00 = d1[i00], d10 = d1[i00+1], d01 = d1[i00+IMW], d11 = d1[i00+IMW+1];
                unsigned h00 = nb_[i00], h10 = nb_[i00+1], h01 = nb_[i00+IMW], h11 = nb_[i00+IMW+1];

                float pxa = (u0f - cx)*inv_fx, pxb = pxa + inv_fx;
                float pya = (v0f - cy)*inv_fy, pyb = pya + inv_fy;
                float a = w00*d00, bb = w10*d10, cc = w01*d01, ee = w11*d11;
                float rVz = (a + bb) + (cc + ee);
                float rVx = (a + cc)*pxa + (bb + ee)*pxb;
                float rVy = (a + bb)*pya + (cc + ee)*pyb;

                // decode biased-ubyte normals: (float)((h>>s)&0xFF) -> single v_cvt_f32_ubyte#
                // bias 127 subtracted after blend (weights sum to 1), scale deferred too
                float q00x = (float)(h00 & 0xFFu);
                float q00y = (float)((h00 >> 8) & 0xFFu);
                float q00z = (float)((h00 >> 16) & 0xFFu);
                float q10x = (float)(h10 & 0xFFu);
                float q10y = (float)((h10 >> 8) & 0xFFu);
                float q10z = (float)((h10 >> 16) & 0xFFu);
                float q01x = (float)(h01 & 0xFFu);
                float q01y = (float)((h01 >> 8) & 0xFFu);
                float q01z = (float)((h01 >> 16) & 0xFFu);
                float q11x = (float)(h11 & 0xFFu);
                float q11y = (float)((h11 >> 8) & 0xFFu);
                float q11z = (float)((h11 >> 16) & 0xFFu);

                float n0x = ((w00*q00x + w10*q10x + w01*q01x + w11*q11x) - 127.f) * inv127;
                float n0y = ((w00*q00y + w10*q10y + w01*q01y + w11*q11y) - 127.f) * inv127;
                float n0z = ((w00*q00z + w10*q10z + w01*q01z + w11*q11z) - 127.f) * inv127;

                float dfx = X - rVx, dfy = Y - rVy, dfz = Z - rVz;
                float d2 = dfx*dfx + dfy*dfy + dfz*dfz + 1e-16f;
                if (d2 <= 0.01f){
                    float res = n0x*dfx + n0y*dfy + n0z*dfz;
                    float N0 = n0x*Rm[0] + n0y*Rm[3] + n0z*Rm[6];
                    float N1 = n0x*Rm[1] + n0y*Rm[4] + n0z*Rm[7];
                    float N2 = n0x*Rm[2] + n0y*Rm[5] + n0z*Rm[8];
                    float cr0 = N1*V0z - N2*V0y;
                    float cr1 = N2*V0x - N0*V0z;
                    float cr2 = N0*V0y - N1*V0x;
                    float ndot = fabsf(N2);
                    float dsh = d0 - 0.4f;
                    float sigz = 0.0012f + 0.0019f*dsh*dsh;
                    float sigma = ndot*sigz + 0.001f;
                    float invs = __builtin_amdgcn_rcpf(sigma + 1e-8f);
                    wres = res*invs;
                    J0 = -cr0*invs; J1 = -cr1*invs; J2 = -cr2*invs;
                    J3 =  N0*invs;  J4 =  N1*invs;  J5 =  N2*invs;
                }
            }

            float Jv[6] = {J0,J1,J2,J3,J4,J5};
            int idx = 0;
            #pragma unroll
            for (int k=0;k<6;k++)
                #pragma unroll
                for (int l=k;l<6;l++){ accv[idx] += Jv[k]*Jv[l]; idx++; }
            #pragma unroll
            for (int k=0;k<6;k++){ accv[idx] += Jv[k]*wres; idx++; }
        }

        pyv += py_step;
    }

    // one wave-level reduction per thread (amortized over 12 pixels)
    #pragma unroll
    for (int i=0;i<27;i++){
        float v = accv[i];
        #pragma unroll
        for (int off=32; off; off >>= 1) v += __shfl_down(v, off);
        accv[i] = v;
    }

    __shared__ float sacc[4][27];
    int wave = threadIdx.x >> 6, lane = threadIdx.x & 63;
    if (lane == 0){
        #pragma unroll
        for (int i=0;i<27;i++) sacc[wave][i] = accv[i];
    }
    __syncthreads();
    if (threadIdx.x < 27){
        float s = sacc[0][threadIdx.x] + sacc[1][threadIdx.x]
                + sacc[2][threadIdx.x] + sacc[3][threadIdx.x];
        atomicAdd(&acc[b*27 + threadIdx.x], s);
    }
}

// ---- per-batch 6x6 solve (f32 Cholesky, fully unrolled -> registers only) + twist update ----
__global__ void solve_kernel(float* __restrict__ acc,
                             float* __restrict__ stateR, float* __restrict__ statet,
                             float* __restrict__ outR, float* __restrict__ outt){
    int b = threadIdx.x;
    if (b >= NB) return;

    float a27[27];
    #pragma unroll
    for (int i=0;i<27;i++) a27[i] = acc[b*27+i];
    #pragma unroll
    for (int i=0;i<27;i++) acc[b*27+i] = 0.f;   // zero for next iteration

    float A[6][6], rhs[6];
    int idx = 0;
    #pragma unroll
    for (int k=0;k<6;k++)
        #pragma unroll
        for (int l=k;l<6;l++){ A[k][l] = a27[idx]; A[l][k] = a27[idx]; idx++; }
    #pragma unroll
    for (int k=0;k<6;k++) rhs[k] = a27[21+k];

    float tr = 0.f;
    #pragma unroll
    for (int k=0;k<6;k++) tr += A[k][k];
    float lm = tr*1e-6f;
    #pragma unroll
    for (int k=0;k<6;k++) A[k][k] += lm;

    // Cholesky A = L L^T (SPD after damping)
    float L[6][6];
    #pragma unroll
    for (int i=0;i<6;i++){
        #pragma unroll
        for (int j=0;j<=i;j++){
            float s = A[i][j];
            #pragma unroll
            for (int k=0;k<j;k++) s -= L[i][k]*L[j][k];
            if (i == j) L[i][i] = sqrtf(s);
            else        L[i][j] = s / L[j][j];
        }
    }
    float y[6];
    #pragma unroll
    for (int i=0;i<6;i++){
        float s = rhs[i];
        #pragma unroll
        for (int k=0;k<i;k++) s -= L[i][k]*y[k];
        y[i] = s / L[i][i];
    }
    float xi[6];
    #pragma unroll
    for (int ii=5; ii>=0; ii--){
        float s = y[ii];
        #pragma unroll
        for (int k=ii+1;k<6;k++) s -= L[k][ii]*xi[k];
        xi[ii] = s / L[ii][ii];
    }

    float w0 = -xi[0], w1 = -xi[1], w2 = -xi[2];
    float th = sqrtf(w0*w0 + w1*w1 + w2*w2 + 1e-24f);
    float ith = 1.f/th;
    float kx = w0*ith, ky = w1*ith, kz = w2*ith;
    float s = sinf(th), cm1 = 1.f - cosf(th);
    float dRm[9];
    dRm[0] = 1.f + cm1*(-ky*ky - kz*kz);
    dRm[1] = -s*kz + cm1*(kx*ky);
    dRm[2] =  s*ky + cm1*(kx*kz);
    dRm[3] =  s*kz + cm1*(kx*ky);
    dRm[4] = 1.f + cm1*(-kx*kx - kz*kz);
    dRm[5] = -s*kx + cm1*(ky*kz);
    dRm[6] = -s*ky + cm1*(kx*kz);
    dRm[7] =  s*kx + cm1*(ky*kz);
    dRm[8] = 1.f + cm1*(-kx*kx - ky*ky);

    float dt0 = -(dRm[0]*xi[3] + dRm[1]*xi[4] + dRm[2]*xi[5]);
    float dt1 = -(dRm[3]*xi[3] + dRm[4]*xi[4] + dRm[5]*xi[5]);
    float dt2 = -(dRm[6]*xi[3] + dRm[7]*xi[4] + dRm[8]*xi[5]);

    float Rm[9], tv[3];
    #pragma unroll
    for (int i=0;i<9;i++) Rm[i] = stateR[b*9+i];
    #pragma unroll
    for (int i=0;i<3;i++) tv[i] = statet[b*3+i];

    float Rn[9];
    #pragma unroll
    for (int i=0;i<3;i++)
        #pragma unroll
        for (int j=0;j<3;j++)
            Rn[i*3+j] = Rm[i*3+0]*dRm[0*3+j] + Rm[i*3+1]*dRm[1*3+j] + Rm[i*3+2]*dRm[2*3+j];
    float tn0 = Rm[0]*dt0 + Rm[1]*dt1 + Rm[2]*dt2 + tv[0];
    float tn1 = Rm[3]*dt0 + Rm[4]*dt1 + Rm[5]*dt2 + tv[1];
    float tn2 = Rm[6]*dt0 + Rm[7]*dt1 + Rm[8]*dt2 + tv[2];

    #pragma unroll
    for (int i=0;i<9;i++){ stateR[b*9+i] = Rn[i]; outR[b*9+i] = Rn[i]; }
    statet[b*3+0] = tn0; outt[b*3+0] = tn0;
    statet[b*3+1] = tn1; outt[b*3+1] = tn1;
    statet[b*3+2] = tn2; outt[b*3+2] = tn2;
}

extern "C" void kernel_launch(void* const* d_in, const int* in_sizes, int n_in,
                              void* d_out, int out_size, void* d_ws, size_t ws_size,
                              hipStream_t stream){
    const float* depth0 = (const float*)d_in[0];
    const float* depth1 = (const float*)d_in[1];
    const float* Kp     = (const float*)d_in[2];
    const float* Rin    = (const float*)d_in[3];
    const float* tin    = (const float*)d_in[4];

    float* out     = (float*)d_out;
    float* outR    = out;
    float* outt    = out + NB*9;
    float* weights = out + NB*12;

    unsigned* nrm  = (unsigned*)d_ws;                     // NB*HW uint (4 B/px, ~20 MB)
    float* stateR  = (float*)(nrm + (size_t)NB*HW);       // NB*9
    float* statet  = stateR + NB*9;                       // NB*3
    unsigned* mm   = (unsigned*)(statet + NB*3);          // 2
    float* acc     = (float*)(mm + 2);                    // NB*27

    init_kernel<<<1, 256, 0, stream>>>(Rin, tin, stateR, statet, mm, acc);
    minmax_kernel<<<dim3(256), 256, 0, stream>>>((const float4*)depth1, mm);
    normal_kernel<<<dim3(HW/256, NB), 256, 0, stream>>>(depth1, Kp, mm, nrm, weights);
    for (int it = 0; it < 3; it++){
        iter_kernel<<<dim3(BPB, NB), 256, 0, stream>>>((const float4*)depth0, depth1, nrm, Kp, stateR, statet, acc);
        solve_kernel<<<1, 64, 0, stream>>>(acc, stateR, statet, outR, outt);
    }
}